// Round 3
// baseline (1457.972 us; speedup 1.0000x reference)
//
#include <hip/hip_runtime.h>
#include <hip/hip_bf16.h>

#define SCAN_B 256

// ---------- preprocessing ----------

__global__ void hist_kernel(const int* __restrict__ edges, int* __restrict__ deg, int e) {
    int i = blockIdx.x * blockDim.x + threadIdx.x;
    if (i < e) atomicAdd(&deg[edges[e + i]], 1);  // dst = edges[1][i]
}

__global__ void scan_pass1(const int* __restrict__ deg, int* __restrict__ partials, int n) {
    __shared__ int sh[SCAN_B];
    int tid = threadIdx.x;
    int i = blockIdx.x * SCAN_B + tid;
    sh[tid] = (i < n) ? deg[i] : 0;
    __syncthreads();
    for (int s = SCAN_B / 2; s > 0; s >>= 1) {
        if (tid < s) sh[tid] += sh[tid + s];
        __syncthreads();
    }
    if (tid == 0) partials[blockIdx.x] = sh[0];
}

__global__ void scan_pass2(int* partials, int nblk) {
    __shared__ int sh[512];
    int tid = threadIdx.x;
    int v = (tid < nblk) ? partials[tid] : 0;
    sh[tid] = v;
    __syncthreads();
    for (int off = 1; off < 512; off <<= 1) {
        int t = (tid >= off) ? sh[tid - off] : 0;
        __syncthreads();
        sh[tid] += t;
        __syncthreads();
    }
    if (tid < nblk) partials[tid] = sh[tid] - v;  // exclusive
}

__global__ void scan_pass3(const int* __restrict__ deg, const int* __restrict__ partials,
                           int* __restrict__ row_off, int* __restrict__ fill_ptr, int n, int e) {
    __shared__ int sh[SCAN_B];
    int tid = threadIdx.x;
    int i = blockIdx.x * SCAN_B + tid;
    int v = (i < n) ? deg[i] : 0;
    sh[tid] = v;
    __syncthreads();
    for (int off = 1; off < SCAN_B; off <<= 1) {
        int t = (tid >= off) ? sh[tid - off] : 0;
        __syncthreads();
        sh[tid] += t;
        __syncthreads();
    }
    if (i < n) {
        int excl = partials[blockIdx.x] + sh[tid] - v;
        row_off[i] = excl;
        fill_ptr[i] = excl;
    }
    if (i == 0) row_off[n] = e;
}

// packed CSR entry: .x = src node, .y = bitcast(norm).
__global__ void fill_kernel(const int* __restrict__ edges, const int* __restrict__ deg,
                            int* __restrict__ fill_ptr, int2* __restrict__ csr_ent, int e) {
    int i = blockIdx.x * blockDim.x + threadIdx.x;
    if (i >= e) return;
    int s = edges[i];
    int d = edges[e + i];
    int pos = atomicAdd(&fill_ptr[d], 1);
    float ds = (float)max(deg[s], 1);
    float dd = (float)max(deg[d], 1);
    int2 ent;
    ent.x = s;
    ent.y = __float_as_int(rsqrtf(ds * dd));
    csr_ent[pos] = ent;
}

// ---------- degree-bucket counting sort (node_order groups equal-degree nodes
// so each conv wave's 8 nodes have ~uniform loop trip count) ----------

__global__ void degbin_hist(const int* __restrict__ deg, int* __restrict__ dbin, int n) {
    int i = blockIdx.x * blockDim.x + threadIdx.x;
    if (i < n) atomicAdd(&dbin[min(deg[i], 255)], 1);
}

__global__ void degbin_scan(const int* __restrict__ dbin, int* __restrict__ dptr) {
    __shared__ int sh[256];
    int tid = threadIdx.x;
    int v = dbin[tid];
    sh[tid] = v;
    __syncthreads();
    for (int off = 1; off < 256; off <<= 1) {
        int t = (tid >= off) ? sh[tid - off] : 0;
        __syncthreads();
        sh[tid] += t;
        __syncthreads();
    }
    dptr[tid] = sh[tid] - v;  // exclusive
}

__global__ void degbin_scatter(const int* __restrict__ deg, int* __restrict__ dptr,
                               int* __restrict__ node_order, int n) {
    int i = blockIdx.x * blockDim.x + threadIdx.x;
    if (i >= n) return;
    int pos = atomicAdd(&dptr[min(deg[i], 255)], 1);
    node_order[pos] = i;
}

// ---------- conv: h_out = 0.9 * A_norm @ h_in + 0.1 * h0 ----------
// 8 lanes per node (float4 each = 128B/node row). Nodes taken through the
// degree-sorted permutation. Unroll-4 with independent accumulators: 4 entry
// loads + 4 gathers in flight per wave.

__global__ __launch_bounds__(256) void conv_kernel(
    const float4* __restrict__ hin4, const float4* __restrict__ h04,
    float4* __restrict__ hout4, const int* __restrict__ row_off,
    const int2* __restrict__ csr_ent, const int* __restrict__ node_order, int n) {
    int gid = blockIdx.x * blockDim.x + threadIdx.x;
    int slot = gid >> 3;
    int q = gid & 7;
    if (slot >= n) return;
    int node = node_order[slot];
    int j0 = row_off[node];
    int j1 = row_off[node + 1];
    float4 a0 = {0.f, 0.f, 0.f, 0.f};
    float4 a1 = {0.f, 0.f, 0.f, 0.f};
    float4 a2 = {0.f, 0.f, 0.f, 0.f};
    float4 a3 = {0.f, 0.f, 0.f, 0.f};
    int j = j0;
    for (; j + 3 < j1; j += 4) {
        int2 e0 = csr_ent[j];
        int2 e1 = csr_ent[j + 1];
        int2 e2 = csr_ent[j + 2];
        int2 e3 = csr_ent[j + 3];
        float4 v0 = hin4[(size_t)e0.x * 8 + q];
        float4 v1 = hin4[(size_t)e1.x * 8 + q];
        float4 v2 = hin4[(size_t)e2.x * 8 + q];
        float4 v3 = hin4[(size_t)e3.x * 8 + q];
        float w0 = __int_as_float(e0.y), w1 = __int_as_float(e1.y);
        float w2 = __int_as_float(e2.y), w3 = __int_as_float(e3.y);
        a0.x += w0 * v0.x; a0.y += w0 * v0.y; a0.z += w0 * v0.z; a0.w += w0 * v0.w;
        a1.x += w1 * v1.x; a1.y += w1 * v1.y; a1.z += w1 * v1.z; a1.w += w1 * v1.w;
        a2.x += w2 * v2.x; a2.y += w2 * v2.y; a2.z += w2 * v2.z; a2.w += w2 * v2.w;
        a3.x += w3 * v3.x; a3.y += w3 * v3.y; a3.z += w3 * v3.z; a3.w += w3 * v3.w;
    }
    for (; j < j1; ++j) {
        int2 e0 = csr_ent[j];
        float w0 = __int_as_float(e0.y);
        float4 v0 = hin4[(size_t)e0.x * 8 + q];
        a0.x += w0 * v0.x; a0.y += w0 * v0.y; a0.z += w0 * v0.z; a0.w += w0 * v0.w;
    }
    size_t oidx = (size_t)node * 8 + q;
    float4 h0v = h04[oidx];
    float4 r;
    r.x = 0.9f * (a0.x + a1.x + a2.x + a3.x) + 0.1f * h0v.x;
    r.y = 0.9f * (a0.y + a1.y + a2.y + a3.y) + 0.1f * h0v.y;
    r.z = 0.9f * (a0.z + a1.z + a2.z + a3.z) + 0.1f * h0v.z;
    r.w = 0.9f * (a0.w + a1.w + a2.w + a3.w) + 0.1f * h0v.w;
    hout4[oidx] = r;
}

// ---------- per-(node,feature) MLP ----------

__global__ __launch_bounds__(256) void mlp_kernel(
    const float* __restrict__ hin, float* __restrict__ hout,
    const float* __restrict__ emb,   // [32][6]
    const float* __restrict__ W1,    // [7][9] row-major
    const float* __restrict__ b1,    // [9]
    const float* __restrict__ W2,    // [9]
    const float* __restrict__ b2,    // [1]
    int total) {
    __shared__ float c[32][9];
    __shared__ float w0[9], w2[9];
    __shared__ float b2s;
    int tid = threadIdx.x;
    for (int i = tid; i < 288; i += blockDim.x) {
        int f = i / 9, jj = i % 9;
        float acc = b1[jj];
#pragma unroll
        for (int k = 0; k < 6; ++k) acc += emb[f * 6 + k] * W1[(1 + k) * 9 + jj];
        c[f][jj] = acc;
    }
    if (tid < 9) { w0[tid] = W1[tid]; w2[tid] = W2[tid]; }
    if (tid == 0) b2s = b2[0];
    __syncthreads();
    int gid = blockIdx.x * blockDim.x + tid;
    if (gid >= total) return;
    int f = gid & 31;
    float xv = hin[gid];
    float acc = b2s;
#pragma unroll
    for (int jj = 0; jj < 9; ++jj)
        acc += fmaxf(xv * w0[jj] + c[f][jj], 0.0f) * w2[jj];
    hout[gid] = acc;
}

// ---------- output projection: out = h @ Wout + bout ----------

__global__ __launch_bounds__(256) void out_kernel(
    const float* __restrict__ h, const float* __restrict__ Wout,
    const float* __restrict__ bout, float* __restrict__ out, int n) {
    __shared__ float w[32 * 16];
    __shared__ float bo[16];
    int tid = threadIdx.x;
    for (int i = tid; i < 512; i += blockDim.x) w[i] = Wout[i];
    if (tid < 16) bo[tid] = bout[tid];
    __syncthreads();
    int gid = blockIdx.x * blockDim.x + tid;
    int node = gid >> 4;
    int cls = gid & 15;
    if (node >= n) return;
    const float* hr = h + node * 32;
    float acc = bo[cls];
#pragma unroll
    for (int f = 0; f < 32; ++f) acc += hr[f] * w[f * 16 + cls];
    out[gid] = acc;
}

extern "C" void kernel_launch(void* const* d_in, const int* in_sizes, int n_in,
                              void* d_out, int out_size, void* d_ws, size_t ws_size,
                              hipStream_t stream) {
    const float* x    = (const float*)d_in[0];
    const int* edges  = (const int*)d_in[1];
    const float* emb  = (const float*)d_in[2];
    const float* W1   = (const float*)d_in[3];
    const float* b1   = (const float*)d_in[4];
    const float* W2   = (const float*)d_in[5];
    const float* b2   = (const float*)d_in[6];
    const float* Wout = (const float*)d_in[7];
    const float* bout = (const float*)d_in[8];
    float* out        = (float*)d_out;

    const int N = in_sizes[0] / 32;
    const int E = in_sizes[1] / 2;

    size_t off = 0;
    auto walloc = [&](size_t bytes) {
        void* p = (char*)d_ws + off;
        off += (bytes + 255) & ~(size_t)255;
        return p;
    };
    int*   deg        = (int*)  walloc((size_t)N * 4);
    int*   row_off    = (int*)  walloc((size_t)(N + 1) * 4);
    int*   fill_ptr   = (int*)  walloc((size_t)N * 4);
    int*   partials   = (int*)  walloc(512 * 4);
    int*   dbin       = (int*)  walloc(256 * 4);
    int*   dptr       = (int*)  walloc(256 * 4);
    int*   node_order = (int*)  walloc((size_t)N * 4);
    int2*  csr_ent    = (int2*) walloc((size_t)E * 8);
    float* bufA       = (float*)walloc((size_t)N * 32 * 4);
    float* bufB       = (float*)walloc((size_t)N * 32 * 4);
    float* bufC       = (float*)walloc((size_t)N * 32 * 4);

    const int nblk_scan = (N + SCAN_B - 1) / SCAN_B;

    hipMemsetAsync(deg, 0, (size_t)N * 4, stream);
    hipMemsetAsync(dbin, 0, 256 * 4, stream);
    hist_kernel<<<(E + 255) / 256, 256, 0, stream>>>(edges, deg, E);
    scan_pass1<<<nblk_scan, SCAN_B, 0, stream>>>(deg, partials, N);
    scan_pass2<<<1, 512, 0, stream>>>(partials, nblk_scan);
    scan_pass3<<<nblk_scan, SCAN_B, 0, stream>>>(deg, partials, row_off, fill_ptr, N, E);
    fill_kernel<<<(E + 255) / 256, 256, 0, stream>>>(edges, deg, fill_ptr, csr_ent, E);
    // degree-sorted permutation
    degbin_hist<<<(N + 255) / 256, 256, 0, stream>>>(deg, dbin, N);
    degbin_scan<<<1, 256, 0, stream>>>(dbin, dptr);
    degbin_scatter<<<(N + 255) / 256, 256, 0, stream>>>(deg, dptr, node_order, N);

    const int conv_blocks = (N * 8 + 255) / 256;
    const int elem_blocks = (N * 32 + 255) / 256;

    // diffuse #1 (h0 = x)
    {
        const float4* hin = (const float4*)x;
        for (int it = 0; it < 10; ++it) {
            float4* ho = (float4*)((it & 1) ? bufB : bufA);
            conv_kernel<<<conv_blocks, 256, 0, stream>>>(hin, (const float4*)x, ho,
                                                         row_off, csr_ent, node_order, N);
            hin = ho;
        }
    }
    // per-(node,feature) MLP: bufB -> bufC
    mlp_kernel<<<elem_blocks, 256, 0, stream>>>(bufB, bufC, emb, W1, b1, W2, b2, N * 32);

    // diffuse #2 (h0 = bufC)
    {
        const float4* hin = (const float4*)bufC;
        for (int it = 0; it < 10; ++it) {
            float4* ho = (float4*)((it & 1) ? bufB : bufA);
            conv_kernel<<<conv_blocks, 256, 0, stream>>>(hin, (const float4*)bufC, ho,
                                                         row_off, csr_ent, node_order, N);
            hin = ho;
        }
    }
    // out = bufB @ Wout + bout
    out_kernel<<<(N * 16 + 255) / 256, 256, 0, stream>>>(bufB, Wout, bout, out, N);
}

// Round 4
// 905.945 us; speedup vs baseline: 1.6093x; 1.6093x over previous
//
#include <hip/hip_runtime.h>
#include <hip/hip_bf16.h>

#define SCAN_B 256

// ---------- preprocessing ----------

__global__ void hist_kernel(const int* __restrict__ edges, int* __restrict__ deg, int e) {
    int i = blockIdx.x * blockDim.x + threadIdx.x;
    if (i < e) atomicAdd(&deg[edges[e + i]], 1);  // dst = edges[1][i]
}

__global__ void scan_pass1(const int* __restrict__ deg, int* __restrict__ partials, int n) {
    __shared__ int sh[SCAN_B];
    int tid = threadIdx.x;
    int i = blockIdx.x * SCAN_B + tid;
    sh[tid] = (i < n) ? deg[i] : 0;
    __syncthreads();
    for (int s = SCAN_B / 2; s > 0; s >>= 1) {
        if (tid < s) sh[tid] += sh[tid + s];
        __syncthreads();
    }
    if (tid == 0) partials[blockIdx.x] = sh[0];
}

__global__ void scan_pass2(int* partials, int nblk) {
    __shared__ int sh[512];
    int tid = threadIdx.x;
    int v = (tid < nblk) ? partials[tid] : 0;
    sh[tid] = v;
    __syncthreads();
    for (int off = 1; off < 512; off <<= 1) {
        int t = (tid >= off) ? sh[tid - off] : 0;
        __syncthreads();
        sh[tid] += t;
        __syncthreads();
    }
    if (tid < nblk) partials[tid] = sh[tid] - v;  // exclusive
}

__global__ void scan_pass3(const int* __restrict__ deg, const int* __restrict__ partials,
                           int* __restrict__ row_off, int* __restrict__ fill_ptr, int n, int e) {
    __shared__ int sh[SCAN_B];
    int tid = threadIdx.x;
    int i = blockIdx.x * SCAN_B + tid;
    int v = (i < n) ? deg[i] : 0;
    sh[tid] = v;
    __syncthreads();
    for (int off = 1; off < SCAN_B; off <<= 1) {
        int t = (tid >= off) ? sh[tid - off] : 0;
        __syncthreads();
        sh[tid] += t;
        __syncthreads();
    }
    if (i < n) {
        int excl = partials[blockIdx.x] + sh[tid] - v;
        row_off[i] = excl;
        fill_ptr[i] = excl;
    }
    if (i == 0) row_off[n] = e;
}

// g-space CSR: src index only (4 B/edge). No per-edge norm.
__global__ void fill_kernel(const int* __restrict__ edges, int* __restrict__ fill_ptr,
                            int* __restrict__ csr_src, int e) {
    int i = blockIdx.x * blockDim.x + threadIdx.x;
    if (i >= e) return;
    int s = edges[i];
    int d = edges[e + i];
    int pos = atomicAdd(&fill_ptr[d], 1);
    csr_src[pos] = s;
}

// per-node constants: rs = rsqrt(max(deg,1)), sq = sqrt(max(deg,1)),
// wdeg = 0.9 * rs^2  (the g-space conv weight)
__global__ void nodeconst_kernel(const int* __restrict__ deg, float* __restrict__ rs,
                                 float* __restrict__ sq, float* __restrict__ wdeg, int n) {
    int i = blockIdx.x * blockDim.x + threadIdx.x;
    if (i >= n) return;
    float d = (float)max(deg[i], 1);
    float r = rsqrtf(d);
    rs[i] = r;
    sq[i] = sqrtf(d);
    wdeg[i] = 0.9f * r * r;
}

// g = rs (.) x   (elementwise row scale)
__global__ void prescale_kernel(const float* __restrict__ x, const float* __restrict__ rs,
                                float* __restrict__ g, int total) {
    int i = blockIdx.x * blockDim.x + threadIdx.x;
    if (i < total) g[i] = x[i] * rs[i >> 5];
}

// ---------- g-space conv: g_out[d] = wdeg[d] * sum_{s in N(d)} g[s] + 0.1 * g0[d]
// 8 lanes per node, each lane owns a float4 (4 feats; 8x16B = 128B row).
// Entry loads are cooperative: lane q loads csr_src[j+q] (one coalesced inst
// per 8-edge round), broadcast via __shfl(width=8); then 8 INDEPENDENT float4
// gathers in flight. Next round's entries prefetched during current gathers.

__global__ __launch_bounds__(256) void conv_kernel(
    const float4* __restrict__ gin, const float4* __restrict__ g0,
    float4* __restrict__ gout, const int* __restrict__ row_off,
    const int* __restrict__ csr_src, const float* __restrict__ wdeg, int n) {
    int gid = blockIdx.x * blockDim.x + threadIdx.x;
    int node = gid >> 3;
    int q = gid & 7;
    if (node >= n) return;
    int j0 = row_off[node];
    int j1 = row_off[node + 1];
    float4 a0 = {0.f, 0.f, 0.f, 0.f};
    float4 a1 = {0.f, 0.f, 0.f, 0.f};
    float4 a2 = {0.f, 0.f, 0.f, 0.f};
    float4 a3 = {0.f, 0.f, 0.f, 0.f};
    int jend = j0 + ((j1 - j0) & ~7);
    int scur = csr_src[j0 + q];  // csr_src padded by 8 ints; OOB-by-row reads are unused
    for (int j = j0; j < jend; j += 8) {
        int snext = csr_src[j + 8 + q];  // prefetch next round (padded region safe)
        int s0 = __shfl(scur, 0, 8), s1 = __shfl(scur, 1, 8);
        int s2 = __shfl(scur, 2, 8), s3 = __shfl(scur, 3, 8);
        int s4 = __shfl(scur, 4, 8), s5 = __shfl(scur, 5, 8);
        int s6 = __shfl(scur, 6, 8), s7 = __shfl(scur, 7, 8);
        float4 v0 = gin[(size_t)s0 * 8 + q];
        float4 v1 = gin[(size_t)s1 * 8 + q];
        float4 v2 = gin[(size_t)s2 * 8 + q];
        float4 v3 = gin[(size_t)s3 * 8 + q];
        float4 v4 = gin[(size_t)s4 * 8 + q];
        float4 v5 = gin[(size_t)s5 * 8 + q];
        float4 v6 = gin[(size_t)s6 * 8 + q];
        float4 v7 = gin[(size_t)s7 * 8 + q];
        a0.x += v0.x; a0.y += v0.y; a0.z += v0.z; a0.w += v0.w;
        a1.x += v1.x; a1.y += v1.y; a1.z += v1.z; a1.w += v1.w;
        a2.x += v2.x; a2.y += v2.y; a2.z += v2.z; a2.w += v2.w;
        a3.x += v3.x; a3.y += v3.y; a3.z += v3.z; a3.w += v3.w;
        a0.x += v4.x; a0.y += v4.y; a0.z += v4.z; a0.w += v4.w;
        a1.x += v5.x; a1.y += v5.y; a1.z += v5.z; a1.w += v5.w;
        a2.x += v6.x; a2.y += v6.y; a2.z += v6.z; a2.w += v6.w;
        a3.x += v7.x; a3.y += v7.y; a3.z += v7.z; a3.w += v7.w;
        scur = snext;
    }
    // tail (deg % 8): scur already holds entries [jend, jend+8)
    int rem = j1 - jend;
    for (int k = 0; k < rem; ++k) {
        int sk = __shfl(scur, k, 8);
        float4 v = gin[(size_t)sk * 8 + q];
        a0.x += v.x; a0.y += v.y; a0.z += v.z; a0.w += v.w;
    }
    float w = wdeg[node];
    float4 g0v = g0[gid];
    float4 r;
    r.x = w * (a0.x + a1.x + a2.x + a3.x) + 0.1f * g0v.x;
    r.y = w * (a0.y + a1.y + a2.y + a3.y) + 0.1f * g0v.y;
    r.z = w * (a0.z + a1.z + a2.z + a3.z) + 0.1f * g0v.z;
    r.w = w * (a0.w + a1.w + a2.w + a3.w) + 0.1f * g0v.w;
    gout[gid] = r;
}

// ---------- per-(node,feature) MLP, fused with g->h and h->g conversions ----------
// reads g, computes h = sq[node]*g, applies MLP, writes g' = rs[node]*mlp(h)

__global__ __launch_bounds__(256) void mlp_kernel(
    const float* __restrict__ gin, float* __restrict__ gout,
    const float* __restrict__ rs, const float* __restrict__ sq,
    const float* __restrict__ emb,   // [32][6]
    const float* __restrict__ W1,    // [7][9] row-major
    const float* __restrict__ b1,    // [9]
    const float* __restrict__ W2,    // [9]
    const float* __restrict__ b2,    // [1]
    int total) {
    __shared__ float c[32][9];
    __shared__ float w0[9], w2[9];
    __shared__ float b2s;
    int tid = threadIdx.x;
    for (int i = tid; i < 288; i += blockDim.x) {
        int f = i / 9, jj = i % 9;
        float acc = b1[jj];
#pragma unroll
        for (int k = 0; k < 6; ++k) acc += emb[f * 6 + k] * W1[(1 + k) * 9 + jj];
        c[f][jj] = acc;
    }
    if (tid < 9) { w0[tid] = W1[tid]; w2[tid] = W2[tid]; }
    if (tid == 0) b2s = b2[0];
    __syncthreads();
    int gid = blockIdx.x * blockDim.x + tid;
    if (gid >= total) return;
    int node = gid >> 5;
    int f = gid & 31;
    float xv = gin[gid] * sq[node];
    float acc = b2s;
#pragma unroll
    for (int jj = 0; jj < 9; ++jj)
        acc += fmaxf(xv * w0[jj] + c[f][jj], 0.0f) * w2[jj];
    gout[gid] = acc * rs[node];
}

// ---------- output projection (fused g->h): out = (sq .* g) @ Wout + bout ----------

__global__ __launch_bounds__(256) void out_kernel(
    const float* __restrict__ g, const float* __restrict__ sq,
    const float* __restrict__ Wout, const float* __restrict__ bout,
    float* __restrict__ out, int n) {
    __shared__ float w[32 * 16];
    __shared__ float bo[16];
    int tid = threadIdx.x;
    for (int i = tid; i < 512; i += blockDim.x) w[i] = Wout[i];
    if (tid < 16) bo[tid] = bout[tid];
    __syncthreads();
    int gid = blockIdx.x * blockDim.x + tid;
    int node = gid >> 4;
    int cls = gid & 15;
    if (node >= n) return;
    const float* gr = g + node * 32;
    float acc = 0.0f;
#pragma unroll
    for (int f = 0; f < 32; ++f) acc += gr[f] * w[f * 16 + cls];
    out[gid] = acc * sq[node] + bo[cls];
}

extern "C" void kernel_launch(void* const* d_in, const int* in_sizes, int n_in,
                              void* d_out, int out_size, void* d_ws, size_t ws_size,
                              hipStream_t stream) {
    const float* x    = (const float*)d_in[0];
    const int* edges  = (const int*)d_in[1];
    const float* emb  = (const float*)d_in[2];
    const float* W1   = (const float*)d_in[3];
    const float* b1   = (const float*)d_in[4];
    const float* W2   = (const float*)d_in[5];
    const float* b2   = (const float*)d_in[6];
    const float* Wout = (const float*)d_in[7];
    const float* bout = (const float*)d_in[8];
    float* out        = (float*)d_out;

    const int N = in_sizes[0] / 32;
    const int E = in_sizes[1] / 2;

    size_t off = 0;
    auto walloc = [&](size_t bytes) {
        void* p = (char*)d_ws + off;
        off += (bytes + 255) & ~(size_t)255;
        return p;
    };
    int*   deg      = (int*)  walloc((size_t)N * 4);
    int*   row_off  = (int*)  walloc((size_t)(N + 1) * 4);
    int*   fill_ptr = (int*)  walloc((size_t)N * 4);
    int*   partials = (int*)  walloc(512 * 4);
    float* rs       = (float*)walloc((size_t)N * 4);
    float* sq       = (float*)walloc((size_t)N * 4);
    float* wdeg     = (float*)walloc((size_t)N * 4);
    int*   csr_src  = (int*)  walloc((size_t)E * 4 + 64);  // +pad: conv prefetch overreads <=8 ints
    float* g0buf    = (float*)walloc((size_t)N * 32 * 4);  // g0 for d1; then MLP output (g0 for d2)
    float* bufA     = (float*)walloc((size_t)N * 32 * 4);
    float* bufB     = (float*)walloc((size_t)N * 32 * 4);

    const int nblk_scan = (N + SCAN_B - 1) / SCAN_B;

    hipMemsetAsync(deg, 0, (size_t)N * 4, stream);
    hist_kernel<<<(E + 255) / 256, 256, 0, stream>>>(edges, deg, E);
    scan_pass1<<<nblk_scan, SCAN_B, 0, stream>>>(deg, partials, N);
    scan_pass2<<<1, 512, 0, stream>>>(partials, nblk_scan);
    scan_pass3<<<nblk_scan, SCAN_B, 0, stream>>>(deg, partials, row_off, fill_ptr, N, E);
    fill_kernel<<<(E + 255) / 256, 256, 0, stream>>>(edges, fill_ptr, csr_src, E);
    nodeconst_kernel<<<(N + 255) / 256, 256, 0, stream>>>(deg, rs, sq, wdeg, N);

    const int conv_blocks = (N * 8 + 255) / 256;
    const int elem_blocks = (N * 32 + 255) / 256;

    prescale_kernel<<<elem_blocks, 256, 0, stream>>>(x, rs, g0buf, N * 32);

    // diffuse #1 in g-space (g0 = g0buf); 10 iters ends in bufB
    {
        const float4* gin = (const float4*)g0buf;
        for (int it = 0; it < 10; ++it) {
            float4* go = (float4*)((it & 1) ? bufB : bufA);
            conv_kernel<<<conv_blocks, 256, 0, stream>>>(gin, (const float4*)g0buf, go,
                                                         row_off, csr_src, wdeg, N);
            gin = go;
        }
    }
    // MLP (g->h, mlp, h->g): bufB -> g0buf (becomes g0 of diffuse #2)
    mlp_kernel<<<elem_blocks, 256, 0, stream>>>(bufB, g0buf, rs, sq, emb, W1, b1, W2, b2, N * 32);

    // diffuse #2 in g-space (g0 = g0buf); ends in bufB
    {
        const float4* gin = (const float4*)g0buf;
        for (int it = 0; it < 10; ++it) {
            float4* go = (float4*)((it & 1) ? bufB : bufA);
            conv_kernel<<<conv_blocks, 256, 0, stream>>>(gin, (const float4*)g0buf, go,
                                                         row_off, csr_src, wdeg, N);
            gin = go;
        }
    }
    // out = (sq .* bufB) @ Wout + bout
    out_kernel<<<(N * 16 + 255) / 256, 256, 0, stream>>>(bufB, sq, Wout, bout, out, N);
}